// Round 6
// baseline (172.277 us; speedup 1.0000x reference)
//
#include <hip/hip_runtime.h>
#include <math.h>

#define DIM 32
#define NK  16
#define LOG2E 1.4426950408889634f

typedef __attribute__((ext_vector_type(8))) short bf16x8;
typedef __attribute__((ext_vector_type(4))) float f32x4;

#define MFMA16 __builtin_amdgcn_mfma_f32_16x16x32_bf16

// ws byte layout (precomputed by gmm_setup_kernel each launch):
// W frags in LANE-LINEAR order: frag f = [k][o16][lane], 16B each.
//   content: lane=(g,c) -> W[k][o16*16+c][g*8 .. g*8+7] (bf16 hi / lo)
#define WHIF_OFF 0       // [16][2][64] 16B frags = 32768 B
#define WLOF_OFF 32768   // [16][2][64] 16B frags = 32768 B
#define HH_OFF  65536    // [NK][DIM] bf16 hi of h*log2e
#define HL_OFF  66560    // [NK][DIM] bf16 lo
#define GH_OFF  67584    // [NK][DIM] bf16 hi of (mu/s2)*log2e
#define GL_OFF  68608    // [NK][DIM] bf16 lo
#define CG_OFF  69632    // [NK] f32: log2(const_k) + sum(mu^2*h)*log2e

// LDS (all wave-local, NO barriers anywhere in the kernel):
//   bias copy per wave: [16 k][32 o] f32 = 2 KB
//   gate-p  per wave: [16 k][256 B] f32, pos=(t*64+g*16)^((row&7)<<4) = 4 KB
#define LDS_BIAS(w) ((w) * 2048)
#define LDS_P(w)    (16384 + (w) * 4096)
#define LDS_TOTAL   (16384 + 32768)     // 48 KB -> 2 blocks/CU fits easily

// Truncation split: x ~= hi + lo keeping ~17 mantissa bits.
__device__ __forceinline__ void split2(float x, short* hi, short* lo) {
  unsigned u = __float_as_uint(x);
  *hi = (short)(u >> 16);
  float hf = __uint_as_float(u & 0xFFFF0000u);
  float l = x - hf;                       // exact residual
  *lo = (short)(__float_as_uint(l) >> 16);
}

__global__ __launch_bounds__(256) void gmm_setup_kernel(
    const float* __restrict__ mu, const float* __restrict__ logsigma,
    const float* __restrict__ W, char* __restrict__ ws)
{
  int i = blockIdx.x * 256 + threadIdx.x;
  // ---- W frags, lane-linear: f = k*128 + o16*64 + lane ----
  if (i < NK * 2 * 64) {
    const int k = i >> 7, o16 = (i >> 6) & 1, lane = i & 63;
    const int c = lane & 15, g = lane >> 4;
    const int o = o16 * 16 + c;
    bf16x8 hi, lo;
    #pragma unroll
    for (int j = 0; j < 8; ++j) {
      short h_, l_;
      split2(W[(k * DIM + o) * DIM + g * 8 + j], &h_, &l_);
      hi[j] = h_; lo[j] = l_;
    }
    ((bf16x8*)(ws + WHIF_OFF))[i] = hi;
    ((bf16x8*)(ws + WLOF_OFF))[i] = lo;
  }
  // ---- gate tables ----
  if (i < NK * DIM) {
    float s2 = __expf(2.0f * logsigma[i]);
    float h = (-0.5f / s2) * LOG2E;       // exp2 later (log2e folded)
    float g = (mu[i] / s2) * LOG2E;
    short a, b;
    split2(h, &a, &b);
    ((short*)(ws + HH_OFF))[i] = a; ((short*)(ws + HL_OFF))[i] = b;
    split2(g, &a, &b);
    ((short*)(ws + GH_OFF))[i] = a; ((short*)(ws + GL_OFF))[i] = b;
  }
  if (i < NK) {
    float acc = 0.0f;
    for (int d = 0; d < DIM; ++d) {
      float s2 = __expf(2.0f * logsigma[i * DIM + d]);
      float m  = mu[i * DIM + d];
      acc += m * m * (-0.5f / s2) * LOG2E - 0.5f * log2f(6.283185307179586f * s2);
    }
    ((float*)(ws + CG_OFF))[i] = acc;
  }
}

// 512-thr block = 8 waves x M=64 samples = 512 samples/block; grid 512 =
// exactly 2 blocks/CU, single generation, 4 waves/SIMD (VGPR capped 128).
// mfma_f32_16x16x32_bf16: A/B frag row/col = lane%16, k=(lane/16)*8+j;
// D: col = lane&15, row = (lane>>4)*4 + reg      [m89-verified]
// No barriers: W hi+lo frags from global (64KB L1/L2-hot); bias + gate-p in
// wave-local LDS. Normalization deferred to the end (no shfl reduce).
__global__ __launch_bounds__(512, 4) void gmm_moe_kernel(
    const float* __restrict__ x,
    const float* __restrict__ bias,
    const char* __restrict__ ws,
    float* __restrict__ out)
{
  __shared__ char lds[LDS_TOTAL];
  const int tid  = threadIdx.x;
  const int wid  = tid >> 6;
  const int lane = tid & 63;
  const int g = lane >> 4;                // k-chunk / row-group
  const int c = lane & 15;                // A-row (sample) & B-col index
  const int sbase = (blockIdx.x * 8 + wid) * 64;

  // ---- stage bias wave-locally (2KB): lane owns 8 consecutive floats ----
  {
    const float4* bsrc = (const float4*)bias;
    float4 b0 = bsrc[lane * 2], b1 = bsrc[lane * 2 + 1];
    *(float4*)(lds + LDS_BIAS(wid) + lane * 32)      = b0;
    *(float4*)(lds + LDS_BIAS(wid) + lane * 32 + 16) = b1;
  }

  // ---- x loads for all 4 tiles (coalesced 2KB/tile/wave) ----
  float4 xa[4][2];
  #pragma unroll
  for (int t = 0; t < 4; ++t) {
    const float4* xp =
        (const float4*)(x + (size_t)(sbase + t * 16 + c) * DIM + g * 8);
    xa[t][0] = xp[0];
    xa[t][1] = xp[1];
  }

  // ---- gate tables (tiny, L2-hot) ----
  const bf16x8 fhh = ((const bf16x8*)(ws + HH_OFF))[c * 4 + g];
  const bf16x8 fhl = ((const bf16x8*)(ws + HL_OFF))[c * 4 + g];
  const bf16x8 fgh = ((const bf16x8*)(ws + GH_OFF))[c * 4 + g];
  const bf16x8 fgl = ((const bf16x8*)(ws + GL_OFF))[c * 4 + g];
  const float  cgv = ((const float*)(ws + CG_OFF))[c];

  // ---- gate: exponent via split-bf16 MFMA, exp2, write UNNORMALIZED p ----
  bf16x8 xh[4], xl[4];
  #pragma unroll
  for (int t = 0; t < 4; ++t) {
    float xv[8] = {xa[t][0].x, xa[t][0].y, xa[t][0].z, xa[t][0].w,
                   xa[t][1].x, xa[t][1].y, xa[t][1].z, xa[t][1].w};
    bf16x8 x2h, x2l;
    #pragma unroll
    for (int j = 0; j < 8; ++j) {
      short h_, l_;
      split2(xv[j], &h_, &l_);
      xh[t][j] = h_; xl[t][j] = l_;
      float q = xv[j] * xv[j];
      split2(q, &h_, &l_);
      x2h[j] = h_; x2l[j] = l_;
    }
    f32x4 e = {cgv, cgv, cgv, cgv};
    e = MFMA16(x2h,   fhh, e, 0, 0, 0);
    e = MFMA16(x2l,   fhh, e, 0, 0, 0);
    e = MFMA16(x2h,   fhl, e, 0, 0, 0);
    e = MFMA16(xh[t], fgh, e, 0, 0, 0);
    e = MFMA16(xl[t], fgh, e, 0, 0, 0);
    e = MFMA16(xh[t], fgl, e, 0, 0, 0);
    // e[r] = log2(p) for sample (g*4+r) of tile t, expert c
    f32x4 wv;
    #pragma unroll
    for (int r = 0; r < 4; ++r) wv[r] = __builtin_amdgcn_exp2f(e[r]);
    // transpose-store: row = expert c, pos swizzled (write ~BW floor)
    *(f32x4*)(lds + LDS_P(wid) + c * 256 +
              ((t * 64 + g * 16) ^ ((c & 7) << 4))) = wv;
  }

  // ---- expert loop: o += p_k*relu(x W_k^T + b_k), psum += p_k ----
  const bf16x8* wfr = (const bf16x8*)ws;  // hi frags at [0,2048), lo at +2048
  f32x4 o0[4], o1[4], psum[4];
  #pragma unroll
  for (int t = 0; t < 4; ++t) {
    o0[t] = (f32x4){0,0,0,0}; o1[t] = (f32x4){0,0,0,0};
    psum[t] = (f32x4){0,0,0,0};
  }

  #pragma unroll
  for (int k = 0; k < NK; ++k) {
    const bf16x8 w0h = wfr[(k * 2 + 0) * 64 + lane];
    const bf16x8 w1h = wfr[(k * 2 + 1) * 64 + lane];
    const bf16x8 w0l = wfr[2048 + (k * 2 + 0) * 64 + lane];
    const bf16x8 w1l = wfr[2048 + (k * 2 + 1) * 64 + lane];
    const float b0 = *(const float*)(lds + LDS_BIAS(wid) + k * 128 + c * 4);
    const float b1 = *(const float*)(lds + LDS_BIAS(wid) + k * 128 + 64 + c * 4);
    #pragma unroll
    for (int t = 0; t < 4; ++t) {
      f32x4 s0 = {b0, b0, b0, b0}, s1 = {b1, b1, b1, b1};
      s0 = MFMA16(xh[t], w0h, s0, 0, 0, 0);
      s0 = MFMA16(xl[t], w0h, s0, 0, 0, 0);
      s0 = MFMA16(xh[t], w0l, s0, 0, 0, 0);
      s1 = MFMA16(xh[t], w1h, s1, 0, 0, 0);
      s1 = MFMA16(xl[t], w1h, s1, 0, 0, 0);
      s1 = MFMA16(xh[t], w1l, s1, 0, 0, 0);
      // unnormalized gate p: broadcast read (4 distinct addrs, swizzle is
      // compile-time on the read side since row = k is unrolled)
      const f32x4 wb = *(const f32x4*)(lds + LDS_P(wid) + k * 256 +
                                       ((t * 64 + g * 16) ^ ((k & 7) << 4)));
      const f32x4 z = {0.0f, 0.0f, 0.0f, 0.0f};
      o0[t] = __builtin_elementwise_fma(wb, __builtin_elementwise_max(s0, z), o0[t]);
      o1[t] = __builtin_elementwise_fma(wb, __builtin_elementwise_max(s1, z), o1[t]);
      psum[t] = psum[t] + wb;
    }
  }

  // ---- deferred normalization + store ----
  #pragma unroll
  for (int t = 0; t < 4; ++t) {
    f32x4 inv;
    #pragma unroll
    for (int r = 0; r < 4; ++r) inv[r] = __builtin_amdgcn_rcpf(psum[t][r]);
    o0[t] = o0[t] * inv;
    o1[t] = o1[t] * inv;
    #pragma unroll
    for (int r = 0; r < 4; ++r) {
      size_t row = (size_t)(sbase + t * 16 + g * 4 + r);
      out[row * DIM + c]      = o0[t][r];
      out[row * DIM + 16 + c] = o1[t][r];
    }
  }
}

extern "C" void kernel_launch(void* const* d_in, const int* in_sizes, int n_in,
                              void* d_out, int out_size, void* d_ws, size_t ws_size,
                              hipStream_t stream) {
  const float* x  = (const float*)d_in[0];   // [B, DIM]
  const float* mu = (const float*)d_in[1];   // [NK, DIM]
  const float* ls = (const float*)d_in[2];   // [NK, DIM]
  const float* W  = (const float*)d_in[3];   // [NK, DIM, DIM]
  const float* bv = (const float*)d_in[4];   // [NK, DIM]
  float* out = (float*)d_out;
  const int B = in_sizes[0] / DIM;

  gmm_setup_kernel<<<8, 256, 0, stream>>>(mu, ls, W, (char*)d_ws);
  // 512 threads = 8 waves x 64 samples = 512 samples/block; grid = B/512
  gmm_moe_kernel<<<B / 512, 512, 0, stream>>>(x, bv, (const char*)d_ws, out);
}